// Round 1
// baseline (766.934 us; speedup 1.0000x reference)
//
#include <hip/hip_runtime.h>

// out[b][pc] = sum_n x[b][n] * kern[n][pc]
//   B=32, N=16384, PC=8192. kern = 537 MB streamed once -> HBM floor ~85 us.
//   R2 (atomic, 698 us) was stall-bound (0.77 TB/s). R3 removes the 8.4M
//   device-scope atomics (ws partials + reduce kernel) and doubles the
//   per-lane load width (dwordx2, unroll 8) for 4x more bytes in flight.

#define B_DIM  32
#define NVOX   16384
#define PC_DIM 8192
#define TPB    256

// ---- main (no-atomic) path geometry ----
#define VEC     2
#define NPAIR   (PC_DIM / VEC)        // 4096 column-pairs
#define KSPLIT  64
#define CHUNK   (NVOX / KSPLIT)       // 256 rows per k-split

// ---- fallback (atomic) path geometry — R2 kernel, verified 698 us ----
#define FB_KSPLIT 32
#define FB_CHUNK  (NVOX / FB_KSPLIT)  // 512

typedef float f32x2 __attribute__((ext_vector_type(2)));

// --- transpose x (B, N) -> xt (N, B), fully coalesced via LDS tile ---
__global__ __launch_bounds__(TPB)
void lp_transpose(const float* __restrict__ x, float* __restrict__ xt) {
    __shared__ float s[B_DIM][TPB + 1];
    const int t  = threadIdx.x;
    const int n0 = blockIdx.x * TPB;
#pragma unroll
    for (int b = 0; b < B_DIM; ++b)
        s[b][t] = x[(size_t)b * NVOX + n0 + t];       // coalesced over n
    __syncthreads();
#pragma unroll
    for (int g = 0; g < B_DIM; ++g) {
        const int flat = g * TPB + t;                  // consecutive out addrs
        const int i = flat >> 5;                       // n offset in tile
        const int b = flat & 31;                       // batch
        xt[(size_t)(n0 + i) * B_DIM + b] = s[b][i];    // coalesced write
    }
}

// --- main GEMM: thread = 2 pc-columns, 64 fp32 accs, no atomics ---
// kern loads: dwordx2, nontemporal (zero reuse -> don't pollute L2/L3).
// x side: wave-uniform xt reads (scalar path). Partials to ws.
__global__ __launch_bounds__(TPB, 4)   // cap VGPR at 128; need ~100
void lp_gemm2(const float* __restrict__ kern, const float* __restrict__ xt,
              float* __restrict__ part) {
    const int cp = blockIdx.x * TPB + threadIdx.x;     // pair index [0,4096)
    const int n0 = blockIdx.y * CHUNK;

    float acc[B_DIM][VEC];
#pragma unroll
    for (int b = 0; b < B_DIM; ++b) {
        acc[b][0] = 0.f;
        acc[b][1] = 0.f;
    }

    const f32x2* kp  = (const f32x2*)kern + (size_t)n0 * NPAIR + cp;
    const float* xr0 = xt + (size_t)n0 * B_DIM;

#pragma unroll 8
    for (int j = 0; j < CHUNK; ++j) {
        const f32x2 kv = __builtin_nontemporal_load(kp + (size_t)j * NPAIR);
        const float* __restrict__ xr = xr0 + (size_t)j * B_DIM;
#pragma unroll
        for (int b = 0; b < B_DIM; ++b) {
            acc[b][0] = fmaf(xr[b], kv.x, acc[b][0]);
            acc[b][1] = fmaf(xr[b], kv.y, acc[b][1]);
        }
    }

    // plain (non-atomic) partial store: part[ks][b][pc], coalesced pairs
    float* pp = part + (size_t)blockIdx.y * ((size_t)B_DIM * PC_DIM);
#pragma unroll
    for (int b = 0; b < B_DIM; ++b) {
        f32x2 v;
        v.x = acc[b][0];
        v.y = acc[b][1];
        __builtin_nontemporal_store(v, (f32x2*)(pp + (size_t)b * PC_DIM) + cp);
    }
}

// --- reduce the KSPLIT partials: out[i] = sum_k part[k][i] ---
__global__ __launch_bounds__(TPB)
void lp_reduce(const float* __restrict__ part, float* __restrict__ out) {
    const int i = blockIdx.x * TPB + threadIdx.x;      // [0, B*PC)
    float s = 0.f;
#pragma unroll
    for (int k = 0; k < KSPLIT; ++k)
        s += __builtin_nontemporal_load(
                 part + (size_t)k * ((size_t)B_DIM * PC_DIM) + i);
    out[i] = s;
}

// ================= R2 fallback (verified): atomic K-split =================
template<bool USE_XT>
__global__ __launch_bounds__(TPB, 4)
void lp_gemm(const float* __restrict__ kern, const float* __restrict__ x,
             const float* __restrict__ xt, float* __restrict__ out) {
    const int c  = blockIdx.x * TPB + threadIdx.x;     // pc column [0,8192)
    const int n0 = blockIdx.y * FB_CHUNK;

    float acc[B_DIM];
#pragma unroll
    for (int b = 0; b < B_DIM; ++b) acc[b] = 0.f;

    const float* kp = kern + (size_t)n0 * PC_DIM + c;

#pragma unroll 4
    for (int j = 0; j < FB_CHUNK; ++j) {
        const float kv = kp[(size_t)j * PC_DIM];
        if (USE_XT) {
            const float* __restrict__ xr = xt + (size_t)(n0 + j) * B_DIM;
#pragma unroll
            for (int b = 0; b < B_DIM; ++b)
                acc[b] = fmaf(xr[b], kv, acc[b]);
        } else {
#pragma unroll
            for (int b = 0; b < B_DIM; ++b)
                acc[b] = fmaf(x[(size_t)b * NVOX + n0 + j], kv, acc[b]);
        }
    }

#pragma unroll
    for (int b = 0; b < B_DIM; ++b)
        atomicAdd(&out[(size_t)b * PC_DIM + c], acc[b]);
}

extern "C" void kernel_launch(void* const* d_in, const int* in_sizes, int n_in,
                              void* d_out, int out_size, void* d_ws, size_t ws_size,
                              hipStream_t stream) {
    const float* x    = (const float*)d_in[0];   // (32, 16384)
    const float* kern = (const float*)d_in[1];   // (16384, 8192)
    float* out = (float*)d_out;                  // (32, 8192)

    const size_t xt_bytes   = (size_t)NVOX * B_DIM * sizeof(float);              // 2 MB
    const size_t part_bytes = (size_t)KSPLIT * B_DIM * PC_DIM * sizeof(float);   // 64 MiB

    if (ws_size >= xt_bytes + part_bytes) {
        // ---- main path: transpose -> no-atomic k-split GEMM -> reduce ----
        float* xt   = (float*)d_ws;
        float* part = (float*)d_ws + (size_t)NVOX * B_DIM;

        lp_transpose<<<NVOX / TPB, TPB, 0, stream>>>(x, xt);

        dim3 grid(NPAIR / TPB, KSPLIT);          // (16, 64) = 1024 blocks
        lp_gemm2<<<grid, TPB, 0, stream>>>(kern, xt, part);

        lp_reduce<<<(B_DIM * PC_DIM) / TPB, TPB, 0, stream>>>(part, out);
    } else {
        // ---- fallback: R2 atomic kernel (verified 698 us) ----
        hipMemsetAsync(out, 0, (size_t)out_size * sizeof(float), stream);
        dim3 grid(PC_DIM / TPB, FB_KSPLIT);      // (32, 32) = 1024 blocks

        if (ws_size >= xt_bytes) {
            float* xt = (float*)d_ws;
            lp_transpose<<<NVOX / TPB, TPB, 0, stream>>>(x, xt);
            lp_gemm<true><<<grid, TPB, 0, stream>>>(kern, x, xt, out);
        } else {
            lp_gemm<false><<<grid, TPB, 0, stream>>>(kern, x, x, out);
        }
    }
}

// Round 3
// 733.740 us; speedup vs baseline: 1.0452x; 1.0452x over previous
//
#include <hip/hip_runtime.h>

// out[b][pc] = sum_n x[b][n] * kern[n][pc]
//   B=32, N=16384, PC=8192. kern = 537 MB streamed once -> HBM floor ~85 us.
//
// R4/R5 theory: R2 (atomic, ~366 us kernel) and R3 (no-atomic dwordx2,
// ~330 us kernel) are the SAME speed -> common bottleneck is the x-side
// scalar-load chain (wave-uniform s_load of 2MB xt misses the 16KB K$ every
// iter, serialized s_load -> lgkmcnt(0) -> 64 FMA). Fix: stage the 32KB xt
// chunk in LDS once per block; inner loop reads x via ds_read_b128 broadcast
// (same-address across wave = conflict-free). VALU floor ~55 us, HBM floor
// ~100 us -> expect gemm ~120-150 us.
// (R4 bench was lost to container failure; resubmitting unchanged.)

#define B_DIM  32
#define NVOX   16384
#define PC_DIM 8192
#define TPB    256

// ---- main (no-atomic) path geometry ----
#define VEC     2
#define NPAIR   (PC_DIM / VEC)        // 4096 column-pairs
#define KSPLIT  64
#define CHUNK   (NVOX / KSPLIT)       // 256 rows per k-split

// ---- fallback (atomic) path geometry — R2 kernel, verified ----
#define FB_KSPLIT 32
#define FB_CHUNK  (NVOX / FB_KSPLIT)  // 512

typedef float f32x2 __attribute__((ext_vector_type(2)));

// --- transpose x (B, N) -> xt (N, B), fully coalesced via LDS tile ---
__global__ __launch_bounds__(TPB)
void lp_transpose(const float* __restrict__ x, float* __restrict__ xt) {
    __shared__ float s[B_DIM][TPB + 1];
    const int t  = threadIdx.x;
    const int n0 = blockIdx.x * TPB;
#pragma unroll
    for (int b = 0; b < B_DIM; ++b)
        s[b][t] = x[(size_t)b * NVOX + n0 + t];       // coalesced over n
    __syncthreads();
#pragma unroll
    for (int g = 0; g < B_DIM; ++g) {
        const int flat = g * TPB + t;                  // consecutive out addrs
        const int i = flat >> 5;                       // n offset in tile
        const int b = flat & 31;                       // batch
        xt[(size_t)(n0 + i) * B_DIM + b] = s[b][i];    // coalesced write
    }
}

// --- main GEMM: thread = 2 pc-columns, 64 fp32 accs, no atomics ---
// kern: dwordx2 nontemporal stream (zero reuse). x: LDS-staged chunk,
// read via float4 -> ds_read_b128 broadcast (all lanes same addr).
__global__ __launch_bounds__(TPB, 4)   // 4 waves/EU -> 4 blocks/CU, VGPR<=128
void lp_gemm2(const float* __restrict__ kern, const float* __restrict__ xt,
              float* __restrict__ part) {
    __shared__ float sx[CHUNK * B_DIM];                // 32 KB
    const int t  = threadIdx.x;
    const int cp = blockIdx.x * TPB + t;               // pair index [0,4096)
    const int n0 = blockIdx.y * CHUNK;

    // stage xt[n0 .. n0+CHUNK)[0..32) -> LDS, coalesced float4 flat copy
    {
        const float4* __restrict__ src =
            (const float4*)(xt + (size_t)n0 * B_DIM);
        float4* dst = (float4*)sx;
#pragma unroll
        for (int i = 0; i < (CHUNK * B_DIM / 4) / TPB; ++i)   // 8 iters
            dst[i * TPB + t] = src[i * TPB + t];
    }
    __syncthreads();

    float acc[B_DIM][VEC];
#pragma unroll
    for (int b = 0; b < B_DIM; ++b) {
        acc[b][0] = 0.f;
        acc[b][1] = 0.f;
    }

    const f32x2* kp = (const f32x2*)kern + (size_t)n0 * NPAIR + cp;

#pragma unroll 4
    for (int j = 0; j < CHUNK; ++j) {
        const f32x2 kv = __builtin_nontemporal_load(kp + (size_t)j * NPAIR);
        const float4* xr = (const float4*)(sx + j * B_DIM);
#pragma unroll
        for (int q = 0; q < B_DIM / 4; ++q) {
            const float4 xv = xr[q];                   // ds_read_b128 broadcast
            acc[4 * q + 0][0] = fmaf(xv.x, kv.x, acc[4 * q + 0][0]);
            acc[4 * q + 0][1] = fmaf(xv.x, kv.y, acc[4 * q + 0][1]);
            acc[4 * q + 1][0] = fmaf(xv.y, kv.x, acc[4 * q + 1][0]);
            acc[4 * q + 1][1] = fmaf(xv.y, kv.y, acc[4 * q + 1][1]);
            acc[4 * q + 2][0] = fmaf(xv.z, kv.x, acc[4 * q + 2][0]);
            acc[4 * q + 2][1] = fmaf(xv.z, kv.y, acc[4 * q + 2][1]);
            acc[4 * q + 3][0] = fmaf(xv.w, kv.x, acc[4 * q + 3][0]);
            acc[4 * q + 3][1] = fmaf(xv.w, kv.y, acc[4 * q + 3][1]);
        }
    }

    // plain (non-atomic) partial store: part[ks][b][pc], coalesced pairs
    float* pp = part + (size_t)blockIdx.y * ((size_t)B_DIM * PC_DIM);
#pragma unroll
    for (int b = 0; b < B_DIM; ++b) {
        f32x2 v;
        v.x = acc[b][0];
        v.y = acc[b][1];
        __builtin_nontemporal_store(v, (f32x2*)(pp + (size_t)b * PC_DIM) + cp);
    }
}

// --- reduce the KSPLIT partials: out[i] = sum_k part[k][i] ---
__global__ __launch_bounds__(TPB)
void lp_reduce(const float* __restrict__ part, float* __restrict__ out) {
    const int i = blockIdx.x * TPB + threadIdx.x;      // [0, B*PC)
    float s = 0.f;
#pragma unroll
    for (int k = 0; k < KSPLIT; ++k)
        s += __builtin_nontemporal_load(
                 part + (size_t)k * ((size_t)B_DIM * PC_DIM) + i);
    out[i] = s;
}

// ================= R2 fallback (verified): atomic K-split =================
template<bool USE_XT>
__global__ __launch_bounds__(TPB, 4)
void lp_gemm(const float* __restrict__ kern, const float* __restrict__ x,
             const float* __restrict__ xt, float* __restrict__ out) {
    const int c  = blockIdx.x * TPB + threadIdx.x;     // pc column [0,8192)
    const int n0 = blockIdx.y * FB_CHUNK;

    float acc[B_DIM];
#pragma unroll
    for (int b = 0; b < B_DIM; ++b) acc[b] = 0.f;

    const float* kp = kern + (size_t)n0 * PC_DIM + c;

#pragma unroll 4
    for (int j = 0; j < FB_CHUNK; ++j) {
        const float kv = kp[(size_t)j * PC_DIM];
        if (USE_XT) {
            const float* __restrict__ xr = xt + (size_t)(n0 + j) * B_DIM;
#pragma unroll
            for (int b = 0; b < B_DIM; ++b)
                acc[b] = fmaf(xr[b], kv, acc[b]);
        } else {
#pragma unroll
            for (int b = 0; b < B_DIM; ++b)
                acc[b] = fmaf(x[(size_t)b * NVOX + n0 + j], kv, acc[b]);
        }
    }

#pragma unroll
    for (int b = 0; b < B_DIM; ++b)
        atomicAdd(&out[(size_t)b * PC_DIM + c], acc[b]);
}

extern "C" void kernel_launch(void* const* d_in, const int* in_sizes, int n_in,
                              void* d_out, int out_size, void* d_ws, size_t ws_size,
                              hipStream_t stream) {
    const float* x    = (const float*)d_in[0];   // (32, 16384)
    const float* kern = (const float*)d_in[1];   // (16384, 8192)
    float* out = (float*)d_out;                  // (32, 8192)

    const size_t xt_bytes   = (size_t)NVOX * B_DIM * sizeof(float);              // 2 MB
    const size_t part_bytes = (size_t)KSPLIT * B_DIM * PC_DIM * sizeof(float);   // 64 MiB

    if (ws_size >= xt_bytes + part_bytes) {
        // ---- main path: transpose -> LDS-staged no-atomic GEMM -> reduce ----
        float* xt   = (float*)d_ws;
        float* part = (float*)d_ws + (size_t)NVOX * B_DIM;

        lp_transpose<<<NVOX / TPB, TPB, 0, stream>>>(x, xt);

        dim3 grid(NPAIR / TPB, KSPLIT);          // (16, 64) = 1024 blocks
        lp_gemm2<<<grid, TPB, 0, stream>>>(kern, xt, part);

        lp_reduce<<<(B_DIM * PC_DIM) / TPB, TPB, 0, stream>>>(part, out);
    } else {
        // ---- fallback: R2 atomic kernel ----
        hipMemsetAsync(out, 0, (size_t)out_size * sizeof(float), stream);
        dim3 grid(PC_DIM / TPB, FB_KSPLIT);      // (32, 32) = 1024 blocks

        if (ws_size >= xt_bytes) {
            float* xt = (float*)d_ws;
            lp_transpose<<<NVOX / TPB, TPB, 0, stream>>>(x, xt);
            lp_gemm<true><<<grid, TPB, 0, stream>>>(kern, x, xt, out);
        } else {
            lp_gemm<false><<<grid, TPB, 0, stream>>>(kern, x, x, out);
        }
    }
}